// Round 1
// baseline (185.438 us; speedup 1.0000x reference)
//
#include <hip/hip_runtime.h>

constexpr int NCLS = 16;
constexpr int NG   = 50;
constexpr int CH   = 21;           // 5 + NCLS
constexpr int N0 = 16384, N1 = 4096, N2 = 1024;
constexpr int NTOT   = N0 + N1 + N2;   // 21504
constexpr int CHUNKS = NTOT / 256;     // 84 (each block fully inside one level)
constexpr float EPSF = 1e-8f;

__global__ __launch_bounds__(256) void dpsv_loss_kernel(
    const float* __restrict__ in0,
    const float* __restrict__ in1,
    const float* __restrict__ in2,
    const float* __restrict__ labels,
    float* __restrict__ out)
{
    const int tid   = threadIdx.x;
    const int b     = blockIdx.x / CHUNKS;
    const int chunk = blockIdx.x % CHUNKS;
    const int p     = chunk * 256 + tid;

    // labels for this batch: raw copy (epilogue) + xy-packed copy (match loop)
    __shared__ float lab[5 * NG];
    __shared__ __align__(8) float labxy[2 * NG];
    if (tid < 5 * NG) lab[tid] = labels[b * 5 * NG + tid];
    if (tid < 2 * NG) labxy[tid] = labels[b * 5 * NG + (tid >> 1) * 5 + (tid & 1)];
    __syncthreads();

    // level decode (block-uniform since 16384 and 4096 are multiples of 256)
    const float* basep; int hw, Wlog, HW; float s;
    if (p < N0)           { basep = in0; hw = p;           Wlog = 7; HW = N0; s = 8.f;  }
    else if (p < N0 + N1) { basep = in1; hw = p - N0;      Wlog = 6; HW = N1; s = 16.f; }
    else                  { basep = in2; hw = p - N0 - N1; Wlog = 5; HW = N2; s = 32.f; }
    const int x = hw & ((1 << Wlog) - 1);
    const int y = hw >> Wlog;
    const float fx = (float)x, fy = (float)y;
    const float cx = (fx + 0.5f) * s;
    const float cy = (fy + 0.5f) * s;
    const float r  = 0.5f * s;

    const float* ch = basep + (size_t)(b * CH) * HW + hw;

    // ---- matching: first GT whose center-region contains (cx,cy) ----
    // min(b_l,b_t,b_r,b_b) > 0  <=>  |cx-gx|<r && |cy-gy|<r
    int matched = 0x7fffffff;
    const float2* lxy = (const float2*)labxy;
    #pragma unroll
    for (int g = 0; g < NG; ++g) {
        float2 l = lxy[g];
        bool inr = (fabsf(cx - l.x) < r) && (fabsf(cy - l.y) < r);
        int cand = inr ? g : 0x7fffffff;
        matched = min(matched, cand);
    }
    const bool fg = (matched != 0x7fffffff);

    // ---- obj term (all anchors) ----
    float loss_part;           // obj + 500*cls accumulated here
    float v0 = 0.f, v1 = 0.f, v2 = 0.f, v3 = 0.f;
    {
        float obj = ch[4 * HW];
        loss_part = fg ? (-1000.f * logf(obj + EPSF))
                       : (-logf(1.f - obj + EPSF));
    }

    // ---- vec + cls terms (fg anchors only; ~0.7% of lanes) ----
    if (fg) {
        const float* lg = &lab[matched * 5];
        float xp = (ch[0]  + fx) * s;
        float yp = (ch[HW] + fy) * s;
        v0 = fabsf((lg[0] - xp) * (1.f / 1024.f));
        v1 = fabsf((lg[1] - yp) * (1.f / 1024.f));
        v2 = fabsf(lg[2] - ch[2 * HW]) * 10.f;
        v3 = fabsf(lg[3] - ch[3 * HW]) * 10.f;
        int ci = (int)lg[4];
        float cls_sum = 0.f;
        #pragma unroll
        for (int c = 0; c < NCLS; ++c) {
            float pc  = ch[(5 + c) * HW];
            float lp  = fmaxf(logf(pc), -100.f);
            float l1p = fmaxf(logf(1.f - pc), -100.f);
            cls_sum += (c == ci) ? -lp : -l1p;
        }
        loss_part += 500.f * cls_sum;
    }

    // ---- reduction: wave shuffle -> LDS -> block atomics ----
    float vals[5] = {loss_part, v0, v1, v2, v3};
    #pragma unroll
    for (int k = 0; k < 5; ++k) {
        float v = vals[k];
        #pragma unroll
        for (int off = 32; off > 0; off >>= 1)
            v += __shfl_xor(v, off, 64);
        vals[k] = v;
    }
    __shared__ float red[4][5];
    const int wave = tid >> 6;
    const int lane = tid & 63;
    if (lane == 0) {
        #pragma unroll
        for (int k = 0; k < 5; ++k) red[wave][k] = vals[k];
    }
    __syncthreads();
    if (tid == 0) {
        float t[5];
        #pragma unroll
        for (int k = 0; k < 5; ++k)
            t[k] = red[0][k] + red[1][k] + red[2][k] + red[3][k];
        atomicAdd(&out[0], t[0] + 10000.f * (t[1] + t[2] + t[3] + t[4]));
        atomicAdd(&out[1], t[1]);
        atomicAdd(&out[2], t[2]);
        atomicAdd(&out[3], t[3]);
        atomicAdd(&out[4], t[4]);
    }
}

extern "C" void kernel_launch(void* const* d_in, const int* in_sizes, int n_in,
                              void* d_out, int out_size, void* d_ws, size_t ws_size,
                              hipStream_t stream) {
    const float* in0    = (const float*)d_in[0];
    const float* in1    = (const float*)d_in[1];
    const float* in2    = (const float*)d_in[2];
    const float* labels = (const float*)d_in[3];
    float* out = (float*)d_out;

    const int B = in_sizes[3] / (5 * NG);   // 32

    // zero accumulators every call (harness does not re-poison between replays)
    hipMemsetAsync(d_out, 0, out_size * sizeof(float), stream);

    dpsv_loss_kernel<<<B * CHUNKS, 256, 0, stream>>>(in0, in1, in2, labels, out);
}

// Round 2
// 21.238 us; speedup vs baseline: 8.7312x; 8.7312x over previous
//
#include <hip/hip_runtime.h>

constexpr int NCLS = 16;
constexpr int NG   = 50;
constexpr int CH   = 21;           // 5 + NCLS
constexpr int N0 = 16384, N1 = 4096, N2 = 1024;
constexpr int NTOT   = N0 + N1 + N2;   // 21504
constexpr int CHUNKS = NTOT / 256;     // 84 (each block fully inside one level)
constexpr int NBLK_B = 32 * CHUNKS;    // 2688 partial-sum rows
constexpr float EPSF = 1e-8f;

__global__ __launch_bounds__(256) void dpsv_main_kernel(
    const float* __restrict__ in0,
    const float* __restrict__ in1,
    const float* __restrict__ in2,
    const float* __restrict__ labels,
    float* __restrict__ ws)
{
    const int tid   = threadIdx.x;
    const int b     = blockIdx.x / CHUNKS;
    const int chunk = blockIdx.x % CHUNKS;
    const int p     = chunk * 256 + tid;

    // full labels for this batch (epilogue needs all 5 fields)
    __shared__ float lab[5 * NG];
    if (tid < 5 * NG) lab[tid] = labels[b * 5 * NG + tid];

    // level decode (block-uniform: 16384 and 4096 are multiples of 256)
    const float* basep; int hw, Wlog, HW; float s; int hw0;
    if (p < N0)           { basep = in0; hw = p;           Wlog = 7; HW = N0; s = 8.f;  hw0 = chunk * 256; }
    else if (p < N0 + N1) { basep = in1; hw = p - N0;      Wlog = 6; HW = N1; s = 16.f; hw0 = chunk * 256 - N0; }
    else                  { basep = in2; hw = p - N0 - N1; Wlog = 5; HW = N2; s = 32.f; hw0 = chunk * 256 - N0 - N1; }
    const int x = hw & ((1 << Wlog) - 1);
    const int y = hw >> Wlog;
    const float fx = (float)x, fy = (float)y;
    const float cx = (fx + 0.5f) * s;
    const float cy = (fy + 0.5f) * s;
    const float r  = 0.5f * s;

    // ---- per-block GT compaction (y-band cull; block spans full rows) ----
    const int y_min = hw0 >> Wlog;
    const int y_max = (hw0 + 255) >> Wlog;
    const float cyLo = ((float)y_min + 0.5f) * s - r;
    const float cyHi = ((float)y_max + 0.5f) * s + r;

    __shared__ int cnt;
    __shared__ float cgx[NG], cgy[NG];
    __shared__ int   cgi[NG];
    if (tid == 0) cnt = 0;
    __syncthreads();
    if (tid < NG) {
        float gx = lab[tid * 5 + 0];
        float gy = lab[tid * 5 + 1];
        if (gy > cyLo && gy < cyHi) {
            int i = atomicAdd(&cnt, 1);
            cgx[i] = gx; cgy[i] = gy; cgi[i] = tid;
        }
    }
    __syncthreads();
    const int ng = cnt;

    // ---- matching: first GT whose center-region contains (cx,cy) ----
    int matched = 0x7fffffff;
    for (int j = 0; j < ng; ++j) {
        bool inr = (fabsf(cx - cgx[j]) < r) && (fabsf(cy - cgy[j]) < r);
        matched = min(matched, inr ? cgi[j] : 0x7fffffff);
    }
    const bool fg = (matched != 0x7fffffff);

    const float* ch = basep + (size_t)(b * CH) * HW + hw;

    // ---- obj term (all anchors) ----
    float loss_part;
    float v0 = 0.f, v1 = 0.f, v2 = 0.f, v3 = 0.f;
    {
        float obj = ch[4 * HW];
        loss_part = fg ? (-1000.f * logf(obj + EPSF))
                       : (-logf(1.f - obj + EPSF));
    }

    // ---- vec + cls terms (fg anchors only; ~0.7% of lanes) ----
    if (fg) {
        const float* lg = &lab[matched * 5];
        float xp = (ch[0]  + fx) * s;
        float yp = (ch[HW] + fy) * s;
        v0 = fabsf((lg[0] - xp) * (1.f / 1024.f));
        v1 = fabsf((lg[1] - yp) * (1.f / 1024.f));
        v2 = fabsf(lg[2] - ch[2 * HW]) * 10.f;
        v3 = fabsf(lg[3] - ch[3 * HW]) * 10.f;
        int ci = (int)lg[4];
        float cls_sum = 0.f;
        #pragma unroll
        for (int c = 0; c < NCLS; ++c) {
            float pc  = ch[(5 + c) * HW];
            float lp  = fmaxf(logf(pc), -100.f);
            float l1p = fmaxf(logf(1.f - pc), -100.f);
            cls_sum += (c == ci) ? -lp : -l1p;
        }
        loss_part += 500.f * cls_sum;
    }

    // ---- reduction: wave shuffle -> LDS -> per-block partial store ----
    float vals[5] = {loss_part, v0, v1, v2, v3};
    #pragma unroll
    for (int k = 0; k < 5; ++k) {
        float v = vals[k];
        #pragma unroll
        for (int off = 32; off > 0; off >>= 1)
            v += __shfl_xor(v, off, 64);
        vals[k] = v;
    }
    __shared__ float red[4][5];
    const int wave = tid >> 6;
    const int lane = tid & 63;
    if (lane == 0) {
        #pragma unroll
        for (int k = 0; k < 5; ++k) red[wave][k] = vals[k];
    }
    __syncthreads();
    if (tid < 5) {
        ws[blockIdx.x * 5 + tid] =
            red[0][tid] + red[1][tid] + red[2][tid] + red[3][tid];
    }
}

__global__ __launch_bounds__(256) void dpsv_reduce_kernel(
    const float* __restrict__ ws, float* __restrict__ out, int nb)
{
    const int tid = threadIdx.x;
    float acc[5] = {0.f, 0.f, 0.f, 0.f, 0.f};
    for (int i = tid; i < nb; i += 256) {
        #pragma unroll
        for (int k = 0; k < 5; ++k) acc[k] += ws[i * 5 + k];
    }
    #pragma unroll
    for (int k = 0; k < 5; ++k) {
        float v = acc[k];
        #pragma unroll
        for (int off = 32; off > 0; off >>= 1)
            v += __shfl_xor(v, off, 64);
        acc[k] = v;
    }
    __shared__ float red[4][5];
    const int wave = tid >> 6;
    const int lane = tid & 63;
    if (lane == 0) {
        #pragma unroll
        for (int k = 0; k < 5; ++k) red[wave][k] = acc[k];
    }
    __syncthreads();
    if (tid == 0) {
        float t[5];
        #pragma unroll
        for (int k = 0; k < 5; ++k)
            t[k] = red[0][k] + red[1][k] + red[2][k] + red[3][k];
        out[0] = t[0] + 10000.f * (t[1] + t[2] + t[3] + t[4]);
        out[1] = t[1];
        out[2] = t[2];
        out[3] = t[3];
        out[4] = t[4];
    }
}

extern "C" void kernel_launch(void* const* d_in, const int* in_sizes, int n_in,
                              void* d_out, int out_size, void* d_ws, size_t ws_size,
                              hipStream_t stream) {
    const float* in0    = (const float*)d_in[0];
    const float* in1    = (const float*)d_in[1];
    const float* in2    = (const float*)d_in[2];
    const float* labels = (const float*)d_in[3];
    float* out = (float*)d_out;
    float* ws  = (float*)d_ws;

    const int B  = in_sizes[3] / (5 * NG);   // 32
    const int nb = B * CHUNKS;               // 2688 partial rows (54 KB in ws)

    dpsv_main_kernel<<<nb, 256, 0, stream>>>(in0, in1, in2, labels, ws);
    dpsv_reduce_kernel<<<1, 256, 0, stream>>>(ws, out, nb);
}